// Round 2
// baseline (344.816 us; speedup 1.0000x reference)
//
#include <hip/hip_runtime.h>

// Problem dims (fixed by the reference):
//   B=8192, P=2, L1=L2=9, N=25, F=128
//   x1: [B,2,9,128] f32, x2: [B,2,9,128] f32, cg: [9,9,25] f32
//   out: [B,1,2,25,128] f32
//
// out[b,0,0,n,f] = sum_{l,m} cg[l,m,n]*(x1e[l]*x2o[m] + x1o[l]*x2e[m])
// out[b,0,1,n,f] = sum_{l,m} cg[l,m,n]*(x1e[l]*x2o[m] + x1o[l]*x2o[m])
// (reference's eoo==eee bug reproduced: both channels share the x1e*x2o term)
//
// Packed-channel formulation: acc[n] is a <2 x float> = {ch0, ch1}. Both
// channels share the cg coefficient, so the inner contraction is ONE
// v_pk_fma_f32 per (l,m,n) instead of two v_fma_f32 — fp32 packed rate is
// 2x scalar on CDNA (157.3 TF peak is the VOP3P rate).

#define B_DIM 8192
#define F_DIM 128
#define L_DIM 9
#define N_DIM 25

typedef __attribute__((ext_vector_type(2))) float v2f;

__global__ __launch_bounds__(256) void tp_kernel(
    const float* __restrict__ x1,
    const float* __restrict__ x2,
    const float* __restrict__ cg,
    float* __restrict__ out)
{
    const int g = blockIdx.x * 256 + threadIdx.x;
    const int b = g >> 7;      // g / F_DIM
    const int f = g & 127;     // g % F_DIM

    const float* x1b = x1 + (size_t)b * 2 * L_DIM * F_DIM + f;
    const float* x2b = x2 + (size_t)b * 2 * L_DIM * F_DIM + f;

    // x2 parity pair per m: {even, odd}. m-loop below is fully unrolled so
    // every index into this register array is compile-time constant.
    v2f x2p[L_DIM];
#pragma unroll
    for (int m = 0; m < L_DIM; ++m) {
        v2f v;
        v.x = __builtin_nontemporal_load(&x2b[m * F_DIM]);            // even
        v.y = __builtin_nontemporal_load(&x2b[(L_DIM + m) * F_DIM]);  // odd
        x2p[m] = v;
    }

    v2f acc[N_DIM];
#pragma unroll
    for (int n = 0; n < N_DIM; ++n) { acc[n] = (v2f)(0.0f); }

    // Outer l loop NOT unrolled: body ~300 insts, keeps code I$-friendly.
    // cg addresses are wave-uniform (SGPR base + uniform l + imm offsets);
    // with __restrict__ the compiler can scalarize them to s_load_* on the
    // SMEM pipe (cg = 8.1 KB, scalar-cache resident). This avoids per-lane
    // VMEM replay and any LDS traffic.
#pragma unroll 1
    for (int l = 0; l < L_DIM; ++l) {
        const float x1e = __builtin_nontemporal_load(&x1b[l * F_DIM]);
        const float x1o = __builtin_nontemporal_load(&x1b[(L_DIM + l) * F_DIM]);
        v2f x1o2; x1o2.x = x1o; x1o2.y = x1o;
        const float* cp_l = cg + l * (L_DIM * N_DIM);
#pragma unroll
        for (int m = 0; m < L_DIM; ++m) {
            const float t = x1e * x2p[m].y;            // shared x1e*x2o term
            v2f tt; tt.x = t; tt.y = t;
            // s = {ch0, ch1} = x1o * {x2e, x2o} + {t, t}  -> one v_pk_fma_f32
            const v2f s = __builtin_elementwise_fma(x1o2, x2p[m], tt);
#pragma unroll
            for (int n = 0; n < N_DIM; ++n) {
                const float c = cp_l[m * N_DIM + n];
                v2f cc; cc.x = c; cc.y = c;
                acc[n] = __builtin_elementwise_fma(cc, s, acc[n]);
            }
        }
    }

    // out[b,0,ch,n,f] -> ((b*2 + ch)*25 + n)*128 + f
    float* ob = out + (size_t)b * 2 * N_DIM * F_DIM + f;
#pragma unroll
    for (int n = 0; n < N_DIM; ++n) {
        __builtin_nontemporal_store(acc[n].x, &ob[n * F_DIM]);
        __builtin_nontemporal_store(acc[n].y, &ob[(N_DIM + n) * F_DIM]);
    }
}

extern "C" void kernel_launch(void* const* d_in, const int* in_sizes, int n_in,
                              void* d_out, int out_size, void* d_ws, size_t ws_size,
                              hipStream_t stream) {
    (void)in_sizes; (void)n_in; (void)out_size; (void)d_ws; (void)ws_size;
    const float* x1 = (const float*)d_in[0];
    const float* x2 = (const float*)d_in[1];
    const float* cg = (const float*)d_in[2];
    float* out = (float*)d_out;

    // B*F threads, one (b,f) pair each: 8192*128/256 = 4096 blocks
    const int threads = 256;
    const int blocks  = (B_DIM * F_DIM) / threads;
    tp_kernel<<<blocks, threads, 0, stream>>>(x1, x2, cg, out);
}